// Round 1
// baseline (216.556 us; speedup 1.0000x reference)
//
#include <hip/hip_runtime.h>

typedef __attribute__((ext_vector_type(8))) short short8;
typedef __attribute__((ext_vector_type(4))) float f32x4;

#define NB 64
#define NC 3
#define NH 384
#define NW 384
#define NPATCH 576
#define NE 768
#define KDIM 768           // NC*16*16
#define MDIM (NB*NPATCH)   // 36864

#define BM 128
#define BN 128
#define BK 64
#define NBLK_N (NE / BN)   // 6

__device__ __forceinline__ unsigned short f2bf(float f) {
    unsigned int u = __builtin_bit_cast(unsigned int, f);
    u += 0x7fffu + ((u >> 16) & 1u);   // round-to-nearest-even
    return (unsigned short)(u >> 16);
}

__global__ __launch_bounds__(256) void patch_embed_gemm(
    const float* __restrict__ x,
    const int* __restrict__ start_h,
    const int* __restrict__ start_w,
    const float* __restrict__ pw,
    const float* __restrict__ pb,
    float* __restrict__ out)
{
    __shared__ __align__(16) unsigned short lA[BM * BK];  // 16 KB, XOR-swizzled
    __shared__ __align__(16) unsigned short lB[BN * BK];  // 16 KB, XOR-swizzled
    __shared__ int baseOff[BM];

    const int tid = threadIdx.x;
    const int bid = blockIdx.x;
    const int bm = bid / NBLK_N;     // 288 m-blocks; 6 consecutive blocks share A-panel
    const int bn = bid % NBLK_N;
    const int m0 = bm * BM;
    const int e0 = bn * BN;

    // per-row patch base offsets into x
    if (tid < BM) {
        int m = m0 + tid;
        int b = m / NPATCH;
        int n = m - b * NPATCH;
        int sh = start_h[b * NPATCH + n];
        int sw = start_w[b * NPATCH + n];
        baseOff[tid] = b * (NC * NH * NW) + sh * NW + sw;
    }

    const int lane = tid & 63;
    const int wv   = tid >> 6;       // wave 0..3
    const int wr   = wv >> 1;        // wave row 0..1  (64 rows each)
    const int wc   = wv & 1;         // wave col 0..1  (64 cols each)
    const int lr   = lane & 15;
    const int lk   = lane >> 4;      // 0..3

    // staging decomposition: 16 threads per LDS row, 4 floats per thread
    const int rt = tid >> 4;         // 0..15
    const int j0 = (tid & 15) * 4;   // float index within 64-wide k-slice
    const int chunk  = j0 >> 3;      // 16B chunk index within row (0..7)
    const int within = j0 & 7;       // element offset inside chunk (0 or 4)

    f32x4 acc[4][4] = {};

    __syncthreads();

    for (int kk = 0; kk < KDIM / BK; ++kk) {
        const int k0 = kk * BK;
        const int c  = k0 >> 8;            // channel
        const int h0 = (k0 & 255) >> 4;    // first patch-row of this k-slice
        const int hh = h0 + (j0 >> 4);
        const int ww = j0 & 15;

        // ---- stage A: gathered patch data, fp32 -> bf16, swizzled LDS ----
        #pragma unroll
        for (int it = 0; it < 8; ++it) {
            int r = it * 16 + rt;
            const float* src = x + baseOff[r] + c * (NH * NW) + hh * NW + ww;
            float f0 = src[0], f1 = src[1], f2 = src[2], f3 = src[3];
            unsigned int u0 = (unsigned int)f2bf(f0) | ((unsigned int)f2bf(f1) << 16);
            unsigned int u1 = (unsigned int)f2bf(f2) | ((unsigned int)f2bf(f3) << 16);
            int off = r * BK + ((chunk ^ (r & 7)) * 8) + within;
            *reinterpret_cast<uint2*>(&lA[off]) = make_uint2(u0, u1);
        }
        // ---- stage B: proj_w rows (dense, aligned), fp32 -> bf16 ----
        #pragma unroll
        for (int it = 0; it < 8; ++it) {
            int r = it * 16 + rt;
            const float4 wf = *reinterpret_cast<const float4*>(
                pw + (size_t)(e0 + r) * KDIM + k0 + j0);
            unsigned int u0 = (unsigned int)f2bf(wf.x) | ((unsigned int)f2bf(wf.y) << 16);
            unsigned int u1 = (unsigned int)f2bf(wf.z) | ((unsigned int)f2bf(wf.w) << 16);
            int off = r * BK + ((chunk ^ (r & 7)) * 8) + within;
            *reinterpret_cast<uint2*>(&lB[off]) = make_uint2(u0, u1);
        }

        __syncthreads();

        // ---- compute: 2 k-substeps x 16 MFMA ----
        #pragma unroll
        for (int ks = 0; ks < 2; ++ks) {
            short8 af[4], bfr[4];
            #pragma unroll
            for (int mi = 0; mi < 4; ++mi) {
                int row = wr * 64 + mi * 16 + lr;
                int off = row * BK + (((ks * 4 + lk) ^ (row & 7)) * 8);
                af[mi] = *reinterpret_cast<const short8*>(&lA[off]);
            }
            #pragma unroll
            for (int ni = 0; ni < 4; ++ni) {
                int row = wc * 64 + ni * 16 + lr;
                int off = row * BK + (((ks * 4 + lk) ^ (row & 7)) * 8);
                bfr[ni] = *reinterpret_cast<const short8*>(&lB[off]);
            }
            #pragma unroll
            for (int mi = 0; mi < 4; ++mi)
                #pragma unroll
                for (int ni = 0; ni < 4; ++ni)
                    acc[mi][ni] = __builtin_amdgcn_mfma_f32_16x16x32_bf16(
                        af[mi], bfr[ni], acc[mi][ni], 0, 0, 0);
        }

        __syncthreads();
    }

    // ---- epilogue: bias + store ----
    float biasv[4];
    #pragma unroll
    for (int ni = 0; ni < 4; ++ni)
        biasv[ni] = pb[e0 + wc * 64 + ni * 16 + lr];

    #pragma unroll
    for (int mi = 0; mi < 4; ++mi) {
        #pragma unroll
        for (int j = 0; j < 4; ++j) {
            int row = m0 + wr * 64 + mi * 16 + lk * 4 + j;
            float* orow = out + (size_t)row * NE + e0 + wc * 64 + lr;
            #pragma unroll
            for (int ni = 0; ni < 4; ++ni)
                orow[ni * 16] = acc[mi][ni][j] + biasv[ni];
        }
    }
}

extern "C" void kernel_launch(void* const* d_in, const int* in_sizes, int n_in,
                              void* d_out, int out_size, void* d_ws, size_t ws_size,
                              hipStream_t stream) {
    const float* x  = (const float*)d_in[0];
    const int* sh   = (const int*)d_in[1];
    const int* sw   = (const int*)d_in[2];
    const float* pw = (const float*)d_in[3];
    const float* pb = (const float*)d_in[4];
    float* out = (float*)d_out;

    dim3 grid((MDIM / BM) * NBLK_N);   // 288 * 6 = 1728
    dim3 block(256);
    hipLaunchKernelGGL(patch_embed_gemm, grid, block, 0, stream,
                       x, sh, sw, pw, pb, out);
}

// Round 2
// 100.402 us; speedup vs baseline: 2.1569x; 2.1569x over previous
//
#include <hip/hip_runtime.h>

typedef __attribute__((ext_vector_type(8))) short short8;
typedef __attribute__((ext_vector_type(4))) float f32x4;
typedef unsigned int u32;

#define NB 64
#define NC 3
#define NH 384
#define NW 384
#define NPATCH 576
#define NE 768
#define KDIM 768           // NC*16*16
#define MDIM (NB*NPATCH)   // 36864

#define BM 128
#define BN 128
#define BK 64
#define NBLK_N (NE / BN)   // 6
#define NBLK_M (MDIM / BM) // 288
#define NWG (NBLK_M * NBLK_N)  // 1728
#define NKK (KDIM / BK)    // 12

#define TILE_B_BYTES (BN * BK * 2)          // 16384
#define WS_B_BYTES (NBLK_N * NKK * TILE_B_BYTES)  // 1,179,648

#define GLOBAL_AS __attribute__((address_space(1)))
#define LDS_AS    __attribute__((address_space(3)))

__device__ __forceinline__ unsigned short f2bf(float f) {
    unsigned int u = __builtin_bit_cast(unsigned int, f);
    u += 0x7fffu + ((u >> 16) & 1u);   // round-to-nearest-even
    return (unsigned short)(u >> 16);
}

__device__ __forceinline__ void gload_lds16(const void* g, void* l) {
    __builtin_amdgcn_global_load_lds((const GLOBAL_AS u32*)g, (LDS_AS u32*)l, 16, 0, 0);
}

// ---- pre-pass: proj_w fp32 [E][K] -> bf16 tile images with XOR swizzle baked in ----
// Tile (bn, kk) is a 16KB byte image: row r (=e&127), 64 bf16, chunk c (16B) at
// byte r*128 + (c ^ (r&7))*16. One thread handles one (e, 8-wide k chunk).
__global__ __launch_bounds__(256) void convert_w(
    const float* __restrict__ pw, unsigned char* __restrict__ wsb)
{
    int id = blockIdx.x * 256 + threadIdx.x;   // 768*96 = 73728 total
    int e  = id / 96;
    int ck = id - e * 96;          // k-chunk 0..95
    int k0 = ck * 8;

    const float4 f0 = *reinterpret_cast<const float4*>(pw + (size_t)e * KDIM + k0);
    const float4 f1 = *reinterpret_cast<const float4*>(pw + (size_t)e * KDIM + k0 + 4);
    u32 a = (u32)f2bf(f0.x) | ((u32)f2bf(f0.y) << 16);
    u32 b = (u32)f2bf(f0.z) | ((u32)f2bf(f0.w) << 16);
    u32 c = (u32)f2bf(f1.x) | ((u32)f2bf(f1.y) << 16);
    u32 d = (u32)f2bf(f1.z) | ((u32)f2bf(f1.w) << 16);

    int bn = e >> 7;
    int r  = e & 127;
    int kk = k0 >> 6;
    int ch = (k0 & 63) >> 3;
    int off = (bn * NKK + kk) * TILE_B_BYTES + r * 128 + ((ch ^ (r & 7)) * 16);
    *reinterpret_cast<uint4*>(wsb + off) = make_uint4(a, b, c, d);
}

template <bool WSB>
__global__ __launch_bounds__(256) void patch_embed_gemm(
    const float* __restrict__ x,
    const int* __restrict__ start_h,
    const int* __restrict__ start_w,
    const float* __restrict__ pw,
    const float* __restrict__ pb,
    const unsigned char* __restrict__ wsb,
    float* __restrict__ out)
{
    __shared__ __align__(16) unsigned short lA[BM * BK];  // 16 KB, XOR-swizzled
    __shared__ __align__(16) unsigned short lB[BN * BK];  // 16 KB, XOR-swizzled
    __shared__ int baseOff[BM];

    const int tid = threadIdx.x;
    // XCD-aware swizzle: 1728 % 8 == 0 -> bijective chunked remap.
    // XCD k receives hardware bids = k mod 8; give it logical ids k*216 .. k*216+215
    // so the 6 bn-blocks sharing an A-panel run consecutively on ONE XCD's L2.
    const int bid  = blockIdx.x;
    const int lbid = (bid & 7) * (NWG / 8) + (bid >> 3);
    const int bm = lbid / NBLK_N;
    const int bn = lbid - bm * NBLK_N;
    const int m0 = bm * BM;
    const int e0 = bn * BN;

    // per-row patch base offsets into x
    if (tid < BM) {
        int m = m0 + tid;
        int b = m / NPATCH;
        int n = m - b * NPATCH;
        int sh = start_h[b * NPATCH + n];
        int sw = start_w[b * NPATCH + n];
        baseOff[tid] = b * (NC * NH * NW) + sh * NW + sw;
    }

    const int lane = tid & 63;
    const int wv   = tid >> 6;       // wave 0..3
    const int wr   = wv >> 1;        // wave row 0..1  (64 rows each)
    const int wc   = wv & 1;         // wave col 0..1  (64 cols each)
    const int lr   = lane & 15;
    const int lk   = lane >> 4;      // 0..3

    // staging decomposition: 16 threads per LDS row, 4 floats per thread
    const int rt = tid >> 4;         // 0..15
    const int j0 = (tid & 15) * 4;   // float index within 64-wide k-slice
    const int chunk  = j0 >> 3;      // 16B chunk index within row (0..7)
    const int within = j0 & 7;       // element offset inside chunk (0 or 4)

    f32x4 acc[4][4] = {};

    __syncthreads();

    for (int kk = 0; kk < NKK; ++kk) {
        const int k0 = kk * BK;
        const int c  = k0 >> 8;            // channel
        const int h0 = (k0 & 255) >> 4;    // first patch-row of this k-slice
        const int hh = h0 + (j0 >> 4);
        const int ww = j0 & 15;

        // ---- stage B ----
        if (WSB) {
            // pre-swizzled bf16 image -> linear LDS via global_load_lds x4 (1KB/issue/wave)
            const unsigned char* src = wsb + (bn * NKK + kk) * TILE_B_BYTES
                                     + wv * 4096 + lane * 16;
            unsigned char* dst = reinterpret_cast<unsigned char*>(lB) + wv * 4096;
            #pragma unroll
            for (int i = 0; i < 4; ++i)
                gload_lds16(src + i * 1024, dst + i * 1024);
        } else {
            #pragma unroll
            for (int it = 0; it < 8; ++it) {
                int r = it * 16 + rt;
                const float4 wf = *reinterpret_cast<const float4*>(
                    pw + (size_t)(e0 + r) * KDIM + k0 + j0);
                u32 u0 = (u32)f2bf(wf.x) | ((u32)f2bf(wf.y) << 16);
                u32 u1 = (u32)f2bf(wf.z) | ((u32)f2bf(wf.w) << 16);
                int off = r * BK + ((chunk ^ (r & 7)) * 8) + within;
                *reinterpret_cast<uint2*>(&lB[off]) = make_uint2(u0, u1);
            }
        }

        // ---- stage A: gathered patch data, fp32 -> bf16, swizzled LDS ----
        #pragma unroll
        for (int it = 0; it < 8; ++it) {
            int r = it * 16 + rt;
            const float* src = x + baseOff[r] + c * (NH * NW) + hh * NW + ww;
            float f0 = src[0], f1 = src[1], f2 = src[2], f3 = src[3];
            u32 u0 = (u32)f2bf(f0) | ((u32)f2bf(f1) << 16);
            u32 u1 = (u32)f2bf(f2) | ((u32)f2bf(f3) << 16);
            int off = r * BK + ((chunk ^ (r & 7)) * 8) + within;
            *reinterpret_cast<uint2*>(&lA[off]) = make_uint2(u0, u1);
        }

        __syncthreads();   // compiler drains vmcnt+lgkmcnt here

        // ---- compute: 2 k-substeps x 16 MFMA ----
        #pragma unroll
        for (int ks = 0; ks < 2; ++ks) {
            short8 af[4], bfr[4];
            #pragma unroll
            for (int mi = 0; mi < 4; ++mi) {
                int row = wr * 64 + mi * 16 + lr;
                int off = row * BK + (((ks * 4 + lk) ^ (row & 7)) * 8);
                af[mi] = *reinterpret_cast<const short8*>(&lA[off]);
            }
            #pragma unroll
            for (int ni = 0; ni < 4; ++ni) {
                int row = wc * 64 + ni * 16 + lr;
                int off = row * BK + (((ks * 4 + lk) ^ (row & 7)) * 8);
                bfr[ni] = *reinterpret_cast<const short8*>(&lB[off]);
            }
            #pragma unroll
            for (int mi = 0; mi < 4; ++mi)
                #pragma unroll
                for (int ni = 0; ni < 4; ++ni)
                    acc[mi][ni] = __builtin_amdgcn_mfma_f32_16x16x32_bf16(
                        af[mi], bfr[ni], acc[mi][ni], 0, 0, 0);
        }

        __syncthreads();
    }

    // ---- epilogue: bias + store ----
    float biasv[4];
    #pragma unroll
    for (int ni = 0; ni < 4; ++ni)
        biasv[ni] = pb[e0 + wc * 64 + ni * 16 + lr];

    #pragma unroll
    for (int mi = 0; mi < 4; ++mi) {
        #pragma unroll
        for (int j = 0; j < 4; ++j) {
            int row = m0 + wr * 64 + mi * 16 + lk * 4 + j;
            float* orow = out + (size_t)row * NE + e0 + wc * 64 + lr;
            #pragma unroll
            for (int ni = 0; ni < 4; ++ni)
                orow[ni * 16] = acc[mi][ni][j] + biasv[ni];
        }
    }
}

extern "C" void kernel_launch(void* const* d_in, const int* in_sizes, int n_in,
                              void* d_out, int out_size, void* d_ws, size_t ws_size,
                              hipStream_t stream) {
    const float* x  = (const float*)d_in[0];
    const int* sh   = (const int*)d_in[1];
    const int* sw   = (const int*)d_in[2];
    const float* pw = (const float*)d_in[3];
    const float* pb = (const float*)d_in[4];
    float* out = (float*)d_out;

    dim3 block(256);
    if (ws_size >= (size_t)WS_B_BYTES) {
        unsigned char* wsb = (unsigned char*)d_ws;
        hipLaunchKernelGGL(convert_w, dim3(288), block, 0, stream, pw, wsb);
        hipLaunchKernelGGL(patch_embed_gemm<true>, dim3(NWG), block, 0, stream,
                           x, sh, sw, pw, pb, wsb, out);
    } else {
        hipLaunchKernelGGL(patch_embed_gemm<false>, dim3(NWG), block, 0, stream,
                           x, sh, sw, pw, pb, (const unsigned char*)nullptr, out);
    }
}